// Round 1
// baseline (423.306 us; speedup 1.0000x reference)
//
#include <hip/hip_runtime.h>
#include <hip/hip_bf16.h>

// EdgeNet fused 2-layer MLP, MI355X (gfx950).
//
// out[m][n2] = relu( sum_k2 relu( sum_k (parent[k]*child[m][k]) * W1[k2][k] + b1[k2] ) * W2[n2][k2] + b2[n2] )
//
// Both layers run as TRANSPOSED MFMA GEMMs: C[n][m] = W · x^T, using
// v_mfma_f32_16x16x32_bf16 with
//   A-frag: lane holds A[row = lane&15][k = 8*(lane>>4)+i], i=0..7   (A = weight)
//   B-frag: lane holds B[k = 8*(lane>>4)+i][col = lane&15]           (B = x^T / h^T)
//   C/D  : lane holds C[row = 4*(lane>>4)+reg][col = lane&15]  (m89-verified)
// => every lane owns a full h row (m = lane&15), so the layer1->layer2 handoff
// is done in-register with ds_bpermute (no LDS h tile, no barriers in loop).
//
// W1 fragments staged in LDS (128 KiB, once per block); W2 fragments read from
// L2 (shared by all blocks, ~0.8 GB total at 32-rows/wave reuse).
// Bias is folded into the MFMA accumulator init.

typedef float f32x4 __attribute__((ext_vector_type(4)));
typedef short bf16x8 __attribute__((ext_vector_type(8)));
typedef unsigned int u32;
typedef u32 u32x4 __attribute__((ext_vector_type(4)));

__device__ __forceinline__ u32 pk2bf(float a, float b) {
    __hip_bfloat162 h2 = __float22bfloat162_rn(make_float2(a, b));
    u32 r;
    __builtin_memcpy(&r, &h2, 4);
    return r;
}

// Pack W (torch layout [n][k] row-major, f32) into per-lane MFMA fragment order:
// halfword[((kt*16 + nt)*64 + lane)*8 + i] = bf16(W[nt*16 + (lane&15)][kt*32 + 8*(lane>>4) + i])
// t in [0,16384): t>>13 selects W1/W2 (W2 at halfword offset 65536).
__global__ __launch_bounds__(256) void pack_w_kernel(
    const float* __restrict__ W1, const float* __restrict__ W2,
    unsigned short* __restrict__ wp)
{
    int t = blockIdx.x * 256 + threadIdx.x;   // 0..16383
    int sel = t >> 13;
    int tt = t & 8191;
    int lane = tt & 63;
    int nt = (tt >> 6) & 15;
    int kt = tt >> 10;
    int n = nt * 16 + (lane & 15);
    int k0 = kt * 32 + 8 * (lane >> 4);
    const float* W = sel ? W2 : W1;
    const float* src = W + n * 256 + k0;
    f32x4 a = *(const f32x4*)src;
    f32x4 b = *(const f32x4*)(src + 4);
    u32x4 d;
    d.x = pk2bf(a.x, a.y);
    d.y = pk2bf(a.z, a.w);
    d.z = pk2bf(b.x, b.y);
    d.w = pk2bf(b.z, b.w);
    *(u32x4*)(wp + (size_t)t * 8) = d;
}

__global__ __launch_bounds__(512) void fused_mlp_kernel(
    const float* __restrict__ child, const float* __restrict__ parent,
    const float* __restrict__ b1, const float* __restrict__ b2,
    const unsigned short* __restrict__ w1p, const unsigned short* __restrict__ w2p,
    float* __restrict__ out, int n_rows)
{
    __shared__ __align__(16) unsigned short w1s[65536];  // 128 KiB W1 fragments
    __shared__ __align__(16) float par[256];
    __shared__ __align__(16) float bias[512];            // [0..255]=b1, [256..511]=b2

    const int tid = threadIdx.x;
    {
        // stage W1 fragments: 8192 x 16B with 512 threads -> 16 iters, coalesced
        const u32x4* s = (const u32x4*)w1p;
        u32x4* d = (u32x4*)w1s;
        #pragma unroll
        for (int i = 0; i < 16; ++i) d[i * 512 + tid] = s[i * 512 + tid];
        if (tid < 256) { par[tid] = parent[tid]; bias[tid] = b1[tid]; }
        else           { bias[tid] = b2[tid - 256]; }
    }
    __syncthreads();
    // No LDS writes below -> no further barriers needed.

    const int lane = tid & 63;
    const int wv = tid >> 6;           // 8 waves, 32 rows each => 256 rows/tile
    const int m16 = lane & 15;
    const int g = lane >> 4;
    // layer1->layer2 bpermute source lanes: ja = 32*(g&1) + m16, jb = ja + 16
    const int ja4 = (32 * (g & 1) + m16) * 4;
    const int jb4 = ja4 + 64;
    const bool hi = (g & 2) != 0;      // selects nt' = 2*kt2 + (g>>1)

    const int n_tiles = (n_rows + 255) >> 8;   // 782 (tail tile has 64 rows = 2 waves)

    for (int tile = blockIdx.x; tile < n_tiles; tile += gridDim.x) {
        const int row0 = tile * 256 + wv * 32;
        if (row0 >= n_rows) continue;          // wave-uniform; n_rows % 32 == 0

        // ---------------- layer 1: h^T = relu(W1 · x^T + b1) ----------------
        f32x4 acc[2][16];
        #pragma unroll
        for (int nt = 0; nt < 16; ++nt) {
            f32x4 bv = *(const f32x4*)&bias[nt * 16 + 4 * g];  // broadcast in 16-lane group
            acc[0][nt] = bv;
            acc[1][nt] = bv;
        }
        const float* crow0 = child + (size_t)(row0 + m16) * 256;
        #pragma unroll
        for (int kt = 0; kt < 8; ++kt) {
            const int k0 = kt * 32 + 8 * g;
            f32x4 p0 = *(const f32x4*)&par[k0];
            f32x4 p1 = *(const f32x4*)&par[k0 + 4];
            bf16x8 bfr[2];
            #pragma unroll
            for (int f = 0; f < 2; ++f) {
                const float* cp = crow0 + f * (16 * 256) + k0;
                f32x4 c0 = *(const f32x4*)cp;       // 32B/lane; wave covers one full
                f32x4 c1 = *(const f32x4*)(cp + 4); // 128B line per row per kt
                c0 *= p0;
                c1 *= p1;
                u32x4 u;
                u.x = pk2bf(c0.x, c0.y);
                u.y = pk2bf(c0.z, c0.w);
                u.z = pk2bf(c1.x, c1.y);
                u.w = pk2bf(c1.z, c1.w);
                bfr[f] = __builtin_bit_cast(bf16x8, u);
            }
            #pragma unroll
            for (int nt = 0; nt < 16; ++nt) {
                bf16x8 af = *(const bf16x8*)&w1s[((kt * 16 + nt) * 64 + lane) * 8];
                acc[0][nt] = __builtin_amdgcn_mfma_f32_16x16x32_bf16(af, bfr[0], acc[0][nt], 0, 0, 0);
                acc[1][nt] = __builtin_amdgcn_mfma_f32_16x16x32_bf16(af, bfr[1], acc[1][nt], 0, 0, 0);
            }
        }

        // relu + pack h to bf16 pairs.
        // Lane j holds h[m = j&15][n = nt*16 + 4*(j>>4) + reg]; pk[f][nt][p] packs regs 2p,2p+1.
        u32 hpk[2][16][2];
        #pragma unroll
        for (int f = 0; f < 2; ++f) {
            #pragma unroll
            for (int nt = 0; nt < 16; ++nt) {
                f32x4 v = acc[f][nt];
                v.x = fmaxf(v.x, 0.0f); v.y = fmaxf(v.y, 0.0f);
                v.z = fmaxf(v.z, 0.0f); v.w = fmaxf(v.w, 0.0f);
                hpk[f][nt][0] = pk2bf(v.x, v.y);
                hpk[f][nt][1] = pk2bf(v.z, v.w);
            }
        }

        // ---------------- layer 2: out^T = relu(W2 · h^T + b2) ----------------
        f32x4 acc2[2][16];
        #pragma unroll
        for (int nt = 0; nt < 16; ++nt) {
            f32x4 bv = *(const f32x4*)&bias[256 + nt * 16 + 4 * g];
            acc2[0][nt] = bv;
            acc2[1][nt] = bv;
        }
        #pragma unroll
        for (int kt2 = 0; kt2 < 8; ++kt2) {
            // B-frag: lane needs h[m16][k2 = kt2*32 + 8g + i]
            //  = lane (16*(2(g&1)+(i>>2)) + m16)'s hpk[2*kt2 + (g>>1)][(i>>1)&1]
            bf16x8 hb[2];
            #pragma unroll
            for (int f = 0; f < 2; ++f) {
                int x0 = __builtin_amdgcn_ds_bpermute(ja4, (int)hpk[f][2 * kt2][0]);
                int x1 = __builtin_amdgcn_ds_bpermute(ja4, (int)hpk[f][2 * kt2][1]);
                int x2 = __builtin_amdgcn_ds_bpermute(jb4, (int)hpk[f][2 * kt2][0]);
                int x3 = __builtin_amdgcn_ds_bpermute(jb4, (int)hpk[f][2 * kt2][1]);
                int y0 = __builtin_amdgcn_ds_bpermute(ja4, (int)hpk[f][2 * kt2 + 1][0]);
                int y1 = __builtin_amdgcn_ds_bpermute(ja4, (int)hpk[f][2 * kt2 + 1][1]);
                int y2 = __builtin_amdgcn_ds_bpermute(jb4, (int)hpk[f][2 * kt2 + 1][0]);
                int y3 = __builtin_amdgcn_ds_bpermute(jb4, (int)hpk[f][2 * kt2 + 1][1]);
                u32x4 u;
                u.x = (u32)(hi ? y0 : x0);
                u.y = (u32)(hi ? y1 : x1);
                u.z = (u32)(hi ? y2 : x2);
                u.w = (u32)(hi ? y3 : x3);
                hb[f] = __builtin_bit_cast(bf16x8, u);
            }
            #pragma unroll
            for (int nt = 0; nt < 16; ++nt) {
                bf16x8 af = *(const bf16x8*)(w2p + (size_t)((kt2 * 16 + nt) * 64 + lane) * 8);
                acc2[0][nt] = __builtin_amdgcn_mfma_f32_16x16x32_bf16(af, hb[0], acc2[0][nt], 0, 0, 0);
                acc2[1][nt] = __builtin_amdgcn_mfma_f32_16x16x32_bf16(af, hb[1], acc2[1][nt], 0, 0, 0);
            }
        }

        // epilogue: relu + f32 store. Lane holds out[m16][nt*16 + 4g + reg]
        // -> per (f,nt): 64B contiguous per row across the 4 g-groups.
        #pragma unroll
        for (int f = 0; f < 2; ++f) {
            float* orow = out + (size_t)(row0 + f * 16 + m16) * 256 + 4 * g;
            #pragma unroll
            for (int nt = 0; nt < 16; ++nt) {
                f32x4 v = acc2[f][nt];
                v.x = fmaxf(v.x, 0.0f); v.y = fmaxf(v.y, 0.0f);
                v.z = fmaxf(v.z, 0.0f); v.w = fmaxf(v.w, 0.0f);
                *(f32x4*)(orow + nt * 16) = v;
            }
        }
    }
}

extern "C" void kernel_launch(void* const* d_in, const int* in_sizes, int n_in,
                              void* d_out, int out_size, void* d_ws, size_t ws_size,
                              hipStream_t stream) {
    const float* parent = (const float*)d_in[0];
    const float* child  = (const float*)d_in[1];
    const float* W1     = (const float*)d_in[2];
    const float* b1     = (const float*)d_in[3];
    const float* W2     = (const float*)d_in[4];
    const float* b2     = (const float*)d_in[5];
    float* out = (float*)d_out;

    unsigned short* wp = (unsigned short*)d_ws;   // [0..65535]=W1 frags, [65536..131071]=W2 frags
    const int n_rows = in_sizes[1] / 256;         // 200000 (multiple of 32)

    pack_w_kernel<<<64, 256, 0, stream>>>(W1, W2, wp);
    fused_mlp_kernel<<<256, 512, 0, stream>>>(child, parent, b1, b2,
                                              wp, wp + 65536, out, n_rows);
}

// Round 2
// 134.438 us; speedup vs baseline: 3.1487x; 3.1487x over previous
//
#include <hip/hip_runtime.h>
#include <hip/hip_bf16.h>

// EdgeNet fused 2-layer MLP, MI355X (gfx950) — round 2.
//
// out[m][n2] = relu( sum_k2 relu( sum_k (parent[k]*child[m][k]) * W1[k2][k] + b1[k2] ) * W2[n2][k2] + b2[n2] )
//
// R1 post-mortem: all pipes <8% busy -> latency-bound from register-pressure
// serialization (128-reg acc x2 + 64-reg hpk + bpermute chains, 2 waves/SIMD).
// R2 structure: one 128-row tile per block (8 waves). Wave w owns OUTPUT
// n-slice [32w, 32w+32) for both layers (acc = 64 regs, phases don't overlap).
// Layer handoff via ONE 64 KiB LDS buffer holding MFMA fragments:
//   phase A: waves stage x-frags (wave w packs rows [16w,16w+16)) -> LDS
//   phase B: layer1 MFMA (B-frags from LDS, W1-frags from L2)
//   phase C: relu/pack h -> same LDS buffer (frag layout for layer 2)
//   phase D: layer2 MFMA + relu + coalesced f32 store
// 3 barriers per block, no in-loop barriers, no bpermute.
//
// MFMA conventions (verified by R1 pass, absmax 0.031):
//   A-frag: lane holds A[row = lane&15][k = 8*(lane>>4)+i], i=0..7
//   B-frag: lane holds B[k = 8*(lane>>4)+i][col = lane&15]
//   C/D  : lane holds C[row = 4*(lane>>4)+reg][col = lane&15]

typedef float f32x4 __attribute__((ext_vector_type(4)));
typedef short bf16x8 __attribute__((ext_vector_type(8)));
typedef unsigned int u32;
typedef u32 u32x4 __attribute__((ext_vector_type(4)));

__device__ __forceinline__ u32 pk2bf(float a, float b) {
    __hip_bfloat162 h2 = __float22bfloat162_rn(make_float2(a, b));
    u32 r;
    __builtin_memcpy(&r, &h2, 4);
    return r;
}

// Pack W (torch layout [n][k] row-major, f32) into per-lane MFMA fragment order:
// halfword[((kt*16 + nt)*64 + lane)*8 + i] = bf16(W[nt*16 + (lane&15)][kt*32 + 8*(lane>>4) + i])
// t in [0,16384): t>>13 selects W1/W2 (W2 at halfword offset 65536).
__global__ __launch_bounds__(256) void pack_w_kernel(
    const float* __restrict__ W1, const float* __restrict__ W2,
    unsigned short* __restrict__ wp)
{
    int t = blockIdx.x * 256 + threadIdx.x;   // 0..16383
    int sel = t >> 13;
    int tt = t & 8191;
    int lane = tt & 63;
    int nt = (tt >> 6) & 15;
    int kt = tt >> 10;
    int n = nt * 16 + (lane & 15);
    int k0 = kt * 32 + 8 * (lane >> 4);
    const float* W = sel ? W2 : W1;
    const float* src = W + n * 256 + k0;
    f32x4 a = *(const f32x4*)src;
    f32x4 b = *(const f32x4*)(src + 4);
    u32x4 d;
    d.x = pk2bf(a.x, a.y);
    d.y = pk2bf(a.z, a.w);
    d.z = pk2bf(b.x, b.y);
    d.w = pk2bf(b.z, b.w);
    *(u32x4*)(wp + (size_t)t * 8) = d;
}

__global__ __launch_bounds__(512, 2) void fused_mlp_kernel(
    const float* __restrict__ child, const float* __restrict__ parent,
    const float* __restrict__ b1, const float* __restrict__ b2,
    const unsigned short* __restrict__ w1p, const unsigned short* __restrict__ w2p,
    float* __restrict__ out, int n_rows)
{
    // 64 KiB fragment buffer: frag (mf, kt) at halfword (mf*8+kt)*512 + lane*8.
    // Holds x-frags in phases A/B, h-frags in phases C/D.
    __shared__ __align__(16) unsigned short xf[32768];

    const int tid = threadIdx.x;
    const int lane = tid & 63;
    const int w = tid >> 6;        // wave 0..7
    const int m16 = lane & 15;
    const int g = lane >> 4;
    const int row0 = blockIdx.x * 128;

    // ---------------- phase A: stage x-frags (x = parent * child, bf16) ----
    if (row0 + w * 16 < n_rows) {              // wave-uniform (n_rows % 64 == 0)
        const float* crow = child + (size_t)(row0 + w * 16 + m16) * 256;
        #pragma unroll
        for (int kt = 0; kt < 8; ++kt) {
            const int k0 = kt * 32 + 8 * g;
            f32x4 p0 = *(const f32x4*)(parent + k0);
            f32x4 p1 = *(const f32x4*)(parent + k0 + 4);
            f32x4 c0 = *(const f32x4*)(crow + k0);
            f32x4 c1 = *(const f32x4*)(crow + k0 + 4);
            c0 *= p0;
            c1 *= p1;
            u32x4 u;
            u.x = pk2bf(c0.x, c0.y);
            u.y = pk2bf(c0.z, c0.w);
            u.z = pk2bf(c1.x, c1.y);
            u.w = pk2bf(c1.z, c1.w);
            *(u32x4*)&xf[((w * 8 + kt) * 64 + lane) * 8] = u;
        }
    }
    __syncthreads();

    // ---------------- phase B: layer 1, wave w computes n-slice [32w,32w+32)
    f32x4 acc1[2][8];
    #pragma unroll
    for (int j = 0; j < 2; ++j) {
        f32x4 bv = *(const f32x4*)(b1 + (2 * w + j) * 16 + 4 * g);
        #pragma unroll
        for (int mf = 0; mf < 8; ++mf) acc1[j][mf] = bv;
    }
    #pragma unroll
    for (int kt = 0; kt < 8; ++kt) {
        bf16x8 a0 = *(const bf16x8*)(w1p + (size_t)((kt * 16 + 2 * w) * 64 + lane) * 8);
        bf16x8 a1 = *(const bf16x8*)(w1p + (size_t)((kt * 16 + 2 * w + 1) * 64 + lane) * 8);
        #pragma unroll
        for (int mf = 0; mf < 8; ++mf) {
            bf16x8 bfrag = *(const bf16x8*)&xf[((mf * 8 + kt) * 64 + lane) * 8];
            acc1[0][mf] = __builtin_amdgcn_mfma_f32_16x16x32_bf16(a0, bfrag, acc1[0][mf], 0, 0, 0);
            acc1[1][mf] = __builtin_amdgcn_mfma_f32_16x16x32_bf16(a1, bfrag, acc1[1][mf], 0, 0, 0);
        }
    }
    __syncthreads();   // all x-frag reads complete before overwrite

    // ---------------- phase C: relu + pack h, write h-frags into xf --------
    // lane holds h[k2 = 32w + 16j + 4g + r][m = mf*16 + m16]
    //   -> frag (mf, kt2=w), lane' = 16*(2j + (g>>1)) + m16, halfword 4*(g&1) + r
    #pragma unroll
    for (int j = 0; j < 2; ++j) {
        #pragma unroll
        for (int mf = 0; mf < 8; ++mf) {
            f32x4 v = acc1[j][mf];
            v.x = fmaxf(v.x, 0.0f); v.y = fmaxf(v.y, 0.0f);
            v.z = fmaxf(v.z, 0.0f); v.w = fmaxf(v.w, 0.0f);
            u32* dst = (u32*)&xf[((mf * 8 + w) * 64 + 16 * (2 * j + (g >> 1)) + m16) * 8 + 4 * (g & 1)];
            dst[0] = pk2bf(v.x, v.y);
            dst[1] = pk2bf(v.z, v.w);
        }
    }
    __syncthreads();

    // ---------------- phase D: layer 2 + epilogue --------------------------
    f32x4 acc2[2][8];
    #pragma unroll
    for (int j = 0; j < 2; ++j) {
        f32x4 bv = *(const f32x4*)(b2 + (2 * w + j) * 16 + 4 * g);
        #pragma unroll
        for (int mf = 0; mf < 8; ++mf) acc2[j][mf] = bv;
    }
    #pragma unroll
    for (int kt = 0; kt < 8; ++kt) {
        bf16x8 a0 = *(const bf16x8*)(w2p + (size_t)((kt * 16 + 2 * w) * 64 + lane) * 8);
        bf16x8 a1 = *(const bf16x8*)(w2p + (size_t)((kt * 16 + 2 * w + 1) * 64 + lane) * 8);
        #pragma unroll
        for (int mf = 0; mf < 8; ++mf) {
            bf16x8 hfrag = *(const bf16x8*)&xf[((mf * 8 + kt) * 64 + lane) * 8];
            acc2[0][mf] = __builtin_amdgcn_mfma_f32_16x16x32_bf16(a0, hfrag, acc2[0][mf], 0, 0, 0);
            acc2[1][mf] = __builtin_amdgcn_mfma_f32_16x16x32_bf16(a1, hfrag, acc2[1][mf], 0, 0, 0);
        }
    }

    // store: lane holds out[m = mf*16+m16][n2 = (2w+j)*16 + 4g + r] -> f32x4
    #pragma unroll
    for (int mf = 0; mf < 8; ++mf) {
        if (row0 + mf * 16 < n_rows) {         // wave-uniform at 16-granularity
            float* orow = out + (size_t)(row0 + mf * 16 + m16) * 256 + 4 * g;
            #pragma unroll
            for (int j = 0; j < 2; ++j) {
                f32x4 v = acc2[j][mf];
                v.x = fmaxf(v.x, 0.0f); v.y = fmaxf(v.y, 0.0f);
                v.z = fmaxf(v.z, 0.0f); v.w = fmaxf(v.w, 0.0f);
                *(f32x4*)(orow + (2 * w + j) * 16) = v;
            }
        }
    }
}

extern "C" void kernel_launch(void* const* d_in, const int* in_sizes, int n_in,
                              void* d_out, int out_size, void* d_ws, size_t ws_size,
                              hipStream_t stream) {
    const float* parent = (const float*)d_in[0];
    const float* child  = (const float*)d_in[1];
    const float* W1     = (const float*)d_in[2];
    const float* b1     = (const float*)d_in[3];
    const float* W2     = (const float*)d_in[4];
    const float* b2     = (const float*)d_in[5];
    float* out = (float*)d_out;

    unsigned short* wp = (unsigned short*)d_ws;   // [0..65535]=W1 frags, [65536..131071]=W2 frags
    const int n_rows = in_sizes[1] / 256;         // 200000

    pack_w_kernel<<<64, 256, 0, stream>>>(W1, W2, wp);

    const int n_tiles = (n_rows + 127) / 128;     // 1563
    fused_mlp_kernel<<<n_tiles, 512, 0, stream>>>(child, parent, b1, b2,
                                                  wp, wp + 65536, out, n_rows);
}